// Round 1
// baseline (4386.776 us; speedup 1.0000x reference)
//
#include <hip/hip_runtime.h>
#include <math.h>

#define Hdim 128
#define NCn  8000
#define NVn  16000
#define NE   60000
#define LITERS 10

__device__ __forceinline__ float elu_f(float x) {
    return x > 0.0f ? x : (expf(x) - 1.0f);
}

// ---------------- init: h = LN(0.1*f*W_in + b_in) ----------------
__global__ void init_kernel(const float* __restrict__ cf, const float* __restrict__ vf,
                            const float* __restrict__ Wc, const float* __restrict__ bc,
                            const float* __restrict__ Wv, const float* __restrict__ bv,
                            const float* __restrict__ gc, const float* __restrict__ bcl,
                            const float* __restrict__ gv, const float* __restrict__ bvl,
                            float* __restrict__ hc, float* __restrict__ hv) {
    int node = blockIdx.x;
    int lane = threadIdx.x;  // 64 threads, 2 elements each
    const float *Win, *bin, *g, *bl;
    float f;
    float* outp;
    if (node < NCn) {
        f = cf[node]; Win = Wc; bin = bc; g = gc; bl = bcl;
        outp = hc + (size_t)node * Hdim;
    } else {
        int n2 = node - NCn;
        f = vf[n2]; Win = Wv; bin = bv; g = gv; bl = bvl;
        outp = hv + (size_t)n2 * Hdim;
    }
    f *= 0.1f;
    float x0 = f * Win[lane] + bin[lane];
    float x1 = f * Win[lane + 64] + bin[lane + 64];
    float s = x0 + x1;
    float sq = x0 * x0 + x1 * x1;
    #pragma unroll
    for (int off = 32; off > 0; off >>= 1) {
        s += __shfl_xor(s, off);
        sq += __shfl_xor(sq, off);
    }
    float m = s * (1.0f / 128.0f);
    float v = sq * (1.0f / 128.0f) - m * m;
    float inv = 1.0f / sqrtf(v + 1e-6f);
    outp[lane]      = g[lane]      * (x0 - m) * inv + bl[lane];
    outp[lane + 64] = g[lane + 64] * (x1 - m) * inv + bl[lane + 64];
}

// ---------------- generic fp32 GEMM ----------------
// out[M x N] = act( [A1(idx1) | A2(idx2)] @ W[:, colOff:colOff+128] + bias ), optionally
// atomically scattered by sidx. BM=64, BN=128, BK=32, 256 threads, 4x8 per-thread tile.
template<bool GATHER, bool HAS_A2, bool DO_ELU, bool SCATTER>
__launch_bounds__(256)
__global__ void gemm_kernel(const float* __restrict__ A1, const float* __restrict__ A2,
                            const int* __restrict__ idx1, const int* __restrict__ idx2,
                            const float* __restrict__ W, int ldW,
                            const float* __restrict__ bias,
                            float* __restrict__ out, int ldOut,
                            const int* __restrict__ sidx, int M) {
    const int K = HAS_A2 ? 256 : 128;
    __shared__ float sA[64 * 33];     // [m][k], stride 33 to break conflicts
    __shared__ float sB[32 * 128];    // [k][n]
    const int tid = threadIdx.x;
    const int blockM = blockIdx.x * 64;
    const int colOff = blockIdx.y * 128;
    const int tx = tid & 15, ty = tid >> 4;
    const int m0 = ty * 4, n0 = tx * 4;

    float acc[4][8];
    #pragma unroll
    for (int r = 0; r < 4; r++)
        #pragma unroll
        for (int c = 0; c < 8; c++) acc[r][c] = 0.0f;

    const int lrow = tid >> 3;        // 0..31
    const int lk   = (tid & 7) * 4;   // 0,4,...,28

    for (int kk = 0; kk < K; kk += 32) {
        // stage A tile (64 rows x 32 k), gathered/concat as needed
        #pragma unroll
        for (int p = 0; p < 2; p++) {
            int r = lrow + p * 32;
            int gm = blockM + r;
            int gmc = gm < M ? gm : M - 1;
            int kglob = kk + lk;
            const float* src;
            if (HAS_A2 && kglob >= 128) {
                int i2 = GATHER ? idx2[gmc] : gmc;
                src = A2 + (size_t)i2 * Hdim + (kglob - 128);
            } else {
                int i1 = GATHER ? idx1[gmc] : gmc;
                src = A1 + (size_t)i1 * Hdim + kglob;
            }
            float4 v = *(const float4*)src;
            sA[r * 33 + lk + 0] = v.x;
            sA[r * 33 + lk + 1] = v.y;
            sA[r * 33 + lk + 2] = v.z;
            sA[r * 33 + lk + 3] = v.w;
        }
        // stage B tile (32 k-rows x 128 cols)
        #pragma unroll
        for (int p = 0; p < 4; p++) {
            int r = (tid >> 5) + p * 8;
            int c = (tid & 31) * 4;
            float4 v = *(const float4*)&W[(size_t)(kk + r) * ldW + colOff + c];
            *(float4*)&sB[r * 128 + c] = v;
        }
        __syncthreads();
        #pragma unroll
        for (int k = 0; k < 32; k++) {
            float a0 = sA[(m0 + 0) * 33 + k];
            float a1 = sA[(m0 + 1) * 33 + k];
            float a2 = sA[(m0 + 2) * 33 + k];
            float a3 = sA[(m0 + 3) * 33 + k];
            float4 b0 = *(const float4*)&sB[k * 128 + n0];
            float4 b1 = *(const float4*)&sB[k * 128 + n0 + 64];
            acc[0][0] += a0 * b0.x; acc[0][1] += a0 * b0.y; acc[0][2] += a0 * b0.z; acc[0][3] += a0 * b0.w;
            acc[0][4] += a0 * b1.x; acc[0][5] += a0 * b1.y; acc[0][6] += a0 * b1.z; acc[0][7] += a0 * b1.w;
            acc[1][0] += a1 * b0.x; acc[1][1] += a1 * b0.y; acc[1][2] += a1 * b0.z; acc[1][3] += a1 * b0.w;
            acc[1][4] += a1 * b1.x; acc[1][5] += a1 * b1.y; acc[1][6] += a1 * b1.z; acc[1][7] += a1 * b1.w;
            acc[2][0] += a2 * b0.x; acc[2][1] += a2 * b0.y; acc[2][2] += a2 * b0.z; acc[2][3] += a2 * b0.w;
            acc[2][4] += a2 * b1.x; acc[2][5] += a2 * b1.y; acc[2][6] += a2 * b1.z; acc[2][7] += a2 * b1.w;
            acc[3][0] += a3 * b0.x; acc[3][1] += a3 * b0.y; acc[3][2] += a3 * b0.z; acc[3][3] += a3 * b0.w;
            acc[3][4] += a3 * b1.x; acc[3][5] += a3 * b1.y; acc[3][6] += a3 * b1.z; acc[3][7] += a3 * b1.w;
        }
        __syncthreads();
    }

    #pragma unroll
    for (int r = 0; r < 4; r++) {
        int gm = blockM + m0 + r;
        if (gm >= M) break;
        if (SCATTER) {
            int trow = sidx[gm];
            #pragma unroll
            for (int c = 0; c < 8; c++) {
                int n = n0 + (c & 3) + ((c >= 4) ? 64 : 0);
                float v = acc[r][c] + bias[colOff + n];
                if (DO_ELU) v = elu_f(v);
                atomicAdd(&out[(size_t)trow * Hdim + n], v);
            }
        } else {
            float4 v0, v1;
            v0.x = acc[r][0] + bias[colOff + n0 + 0];
            v0.y = acc[r][1] + bias[colOff + n0 + 1];
            v0.z = acc[r][2] + bias[colOff + n0 + 2];
            v0.w = acc[r][3] + bias[colOff + n0 + 3];
            v1.x = acc[r][4] + bias[colOff + n0 + 64];
            v1.y = acc[r][5] + bias[colOff + n0 + 65];
            v1.z = acc[r][6] + bias[colOff + n0 + 66];
            v1.w = acc[r][7] + bias[colOff + n0 + 67];
            if (DO_ELU) {
                v0.x = elu_f(v0.x); v0.y = elu_f(v0.y); v0.z = elu_f(v0.z); v0.w = elu_f(v0.w);
                v1.x = elu_f(v1.x); v1.y = elu_f(v1.y); v1.z = elu_f(v1.z); v1.w = elu_f(v1.w);
            }
            *(float4*)&out[(size_t)gm * ldOut + colOff + n0]      = v0;
            *(float4*)&out[(size_t)gm * ldOut + colOff + n0 + 64] = v1;
        }
    }
}

// ---------------- GRU gates (reset_after=True, gate order z,r,h) ----------------
__global__ void gate_kernel(const float* __restrict__ xa, const float* __restrict__ ha,
                            float* __restrict__ h, int N) {
    int g = blockIdx.x * blockDim.x + threadIdx.x;
    if (g >= N * Hdim) return;
    int i = g >> 7, t = g & 127;
    const float* xr = xa + (size_t)i * 384;
    const float* hr = ha + (size_t)i * 384;
    float z  = 1.0f / (1.0f + expf(-(xr[t] + hr[t])));
    float rr = 1.0f / (1.0f + expf(-(xr[128 + t] + hr[128 + t])));
    float hh = tanhf(xr[256 + t] + rr * hr[256 + t]);
    float hold = h[g];
    h[g] = z * hold + (1.0f - z) * hh;
}

// ---------------- final: out[i] = dot(hv[i], Wf) + bf ----------------
__global__ void final_kernel(const float* __restrict__ hv, const float* __restrict__ Wf,
                             const float* __restrict__ bf, float* __restrict__ out) {
    int node = blockIdx.x * 4 + (threadIdx.x >> 6);
    int lane = threadIdx.x & 63;
    const float* row = hv + (size_t)node * Hdim;
    float s = row[lane] * Wf[lane] + row[lane + 64] * Wf[lane + 64];
    #pragma unroll
    for (int off = 32; off > 0; off >>= 1) s += __shfl_xor(s, off);
    if (lane == 0) out[node] = s + bf[0];
}

__global__ void zero_kernel(float4* __restrict__ p, int n4) {
    int i = blockIdx.x * blockDim.x + threadIdx.x;
    if (i < n4) p[i] = make_float4(0.f, 0.f, 0.f, 0.f);
}

extern "C" void kernel_launch(void* const* d_in, const int* in_sizes, int n_in,
                              void* d_out, int out_size, void* d_ws, size_t ws_size,
                              hipStream_t stream) {
    const float* cf      = (const float*)d_in[0];
    const float* vf      = (const float*)d_in[1];
    const int*   c2v_src = (const int*)d_in[2];
    const int*   c2v_tgt = (const int*)d_in[3];
    const int*   v2c_src = (const int*)d_in[4];
    const int*   v2c_tgt = (const int*)d_in[5];
    const float* Wc_in   = (const float*)d_in[6];
    const float* bc_in   = (const float*)d_in[7];
    const float* Wv_in   = (const float*)d_in[8];
    const float* bv_in   = (const float*)d_in[9];
    const float* gc_ln   = (const float*)d_in[10];
    const float* bc_ln   = (const float*)d_in[11];
    const float* gv_ln   = (const float*)d_in[12];
    const float* bv_ln   = (const float*)d_in[13];
    const float* Wmsg_c  = (const float*)d_in[14];
    const float* bmsg_c  = (const float*)d_in[15];
    const float* Wmsg_v  = (const float*)d_in[16];
    const float* bmsg_v  = (const float*)d_in[17];
    const float* Wns_c   = (const float*)d_in[18];
    const float* bns_c   = (const float*)d_in[19];
    const float* Wns_v   = (const float*)d_in[20];
    const float* bns_v   = (const float*)d_in[21];
    const float* Wg_c    = (const float*)d_in[22];
    const float* Ug_c    = (const float*)d_in[23];
    const float* bg_c    = (const float*)d_in[24];
    const float* Wg_v    = (const float*)d_in[25];
    const float* Ug_v    = (const float*)d_in[26];
    const float* bg_v    = (const float*)d_in[27];
    const float* Wf      = (const float*)d_in[28];
    const float* bf      = (const float*)d_in[29];
    float* out = (float*)d_out;

    // workspace layout (floats). total = 21,504,000 floats = 86.0 MB
    float* ws    = (float*)d_ws;
    float* hc    = ws;                   // NC*128 = 1,024,000
    float* hv    = hc    + 1024000;      // NV*128 = 2,048,000
    float* agg_c = hv    + 2048000;      // 1,024,000
    float* agg_v = agg_c + 1024000;      // 2,048,000 (contiguous with agg_c for one zero pass)
    float* upd_c = agg_v + 2048000;      // 1,024,000
    float* upd_v = upd_c + 1024000;      // 2,048,000
    float* G     = upd_v + 2048000;      // 12,288,000 (GRU scratch, reused c then v)
    float* xa_c  = G;
    float* ha_c  = G + 3072000;
    float* xa_v  = G;
    float* ha_v  = G + 6144000;

    init_kernel<<<NCn + NVn, 64, 0, stream>>>(cf, vf, Wc_in, bc_in, Wv_in, bv_in,
                                              gc_ln, bc_ln, gv_ln, bv_ln, hc, hv);

    const int gridE  = (NE + 63) / 64;   // 938
    const int gridC  = NCn / 64;         // 125
    const int gridV  = NVn / 64;         // 250

    for (int it = 0; it < LITERS; it++) {
        // zero agg_c + agg_v together (3,072,000 floats = 768,000 float4)
        zero_kernel<<<3000, 256, 0, stream>>>((float4*)agg_c, 768000);

        // v->c messages: elu(concat(hv[src], hc[tgt]) @ Wmsg_c + b) scatter-> agg_c
        gemm_kernel<true, true, true, true><<<dim3(gridE, 1), 256, 0, stream>>>(
            hv, hc, v2c_src, v2c_tgt, Wmsg_c, 128, bmsg_c, agg_c, 128, v2c_tgt, NE);
        // c->v messages
        gemm_kernel<true, true, true, true><<<dim3(gridE, 1), 256, 0, stream>>>(
            hc, hv, c2v_src, c2v_tgt, Wmsg_v, 128, bmsg_v, agg_v, 128, c2v_tgt, NE);

        // next-state: elu(concat(h, agg) @ Wns + b)
        gemm_kernel<false, true, true, false><<<dim3(gridC, 1), 256, 0, stream>>>(
            hc, agg_c, nullptr, nullptr, Wns_c, 128, bns_c, upd_c, 128, nullptr, NCn);
        gemm_kernel<false, true, true, false><<<dim3(gridV, 1), 256, 0, stream>>>(
            hv, agg_v, nullptr, nullptr, Wns_v, 128, bns_v, upd_v, 128, nullptr, NVn);

        // GRU c: xa = upd_c@Wg_c + bg[0]; ha = hc@Ug_c + bg[1]; gates in-place on hc
        gemm_kernel<false, false, false, false><<<dim3(gridC, 3), 256, 0, stream>>>(
            upd_c, nullptr, nullptr, nullptr, Wg_c, 384, bg_c, xa_c, 384, nullptr, NCn);
        gemm_kernel<false, false, false, false><<<dim3(gridC, 3), 256, 0, stream>>>(
            hc, nullptr, nullptr, nullptr, Ug_c, 384, bg_c + 384, ha_c, 384, nullptr, NCn);
        gate_kernel<<<(NCn * Hdim) / 256, 256, 0, stream>>>(xa_c, ha_c, hc, NCn);

        // GRU v
        gemm_kernel<false, false, false, false><<<dim3(gridV, 3), 256, 0, stream>>>(
            upd_v, nullptr, nullptr, nullptr, Wg_v, 384, bg_v, xa_v, 384, nullptr, NVn);
        gemm_kernel<false, false, false, false><<<dim3(gridV, 3), 256, 0, stream>>>(
            hv, nullptr, nullptr, nullptr, Ug_v, 384, bg_v + 384, ha_v, 384, nullptr, NVn);
        gate_kernel<<<(NVn * Hdim) / 256, 256, 0, stream>>>(xa_v, ha_v, hv, NVn);
    }

    final_kernel<<<NVn / 4, 256, 0, stream>>>(hv, Wf, bf, out);
}

// Round 2
// 1488.836 us; speedup vs baseline: 2.9464x; 2.9464x over previous
//
#include <hip/hip_runtime.h>
#include <hip/hip_bf16.h>
#include <math.h>

#define Hdim 128
#define NCn  8000
#define NVn  16000
#define NE   60000
#define LITERS 10

typedef __attribute__((ext_vector_type(8))) short s8v;   // 8 x bf16 (4 VGPRs)
typedef __attribute__((ext_vector_type(4))) float f4v;   // MFMA acc

__device__ __forceinline__ float elu_f(float x) { return x > 0.0f ? x : (expf(x) - 1.0f); }
__device__ __forceinline__ unsigned short f2b(float x) {
    __hip_bfloat16 h = __float2bfloat16(x); return *(unsigned short*)&h;
}
__device__ __forceinline__ float b2f(unsigned short u) {
    __hip_bfloat16 h; *(unsigned short*)&h = u; return __bfloat162float(h);
}

// ---------------- init: h = LN(0.1*f*W_in + b_in), fp32 + bf16 mirror ----------------
__global__ void init_kernel(const float* __restrict__ cf, const float* __restrict__ vf,
                            const float* __restrict__ Wc, const float* __restrict__ bc,
                            const float* __restrict__ Wv, const float* __restrict__ bv,
                            const float* __restrict__ gc, const float* __restrict__ bcl,
                            const float* __restrict__ gv, const float* __restrict__ bvl,
                            float* __restrict__ hc, float* __restrict__ hv,
                            unsigned short* __restrict__ hcb, unsigned short* __restrict__ hvb) {
    int node = blockIdx.x;
    int lane = threadIdx.x;  // 64 threads, 2 elements each
    const float *Win, *bin, *g, *bl;
    float f;
    float* outp;
    unsigned short* outb;
    if (node < NCn) {
        f = cf[node]; Win = Wc; bin = bc; g = gc; bl = bcl;
        outp = hc + (size_t)node * Hdim; outb = hcb + (size_t)node * Hdim;
    } else {
        int n2 = node - NCn;
        f = vf[n2]; Win = Wv; bin = bv; g = gv; bl = bvl;
        outp = hv + (size_t)n2 * Hdim; outb = hvb + (size_t)n2 * Hdim;
    }
    f *= 0.1f;
    float x0 = f * Win[lane] + bin[lane];
    float x1 = f * Win[lane + 64] + bin[lane + 64];
    float s = x0 + x1;
    float sq = x0 * x0 + x1 * x1;
    #pragma unroll
    for (int off = 32; off > 0; off >>= 1) {
        s += __shfl_xor(s, off);
        sq += __shfl_xor(sq, off);
    }
    float m = s * (1.0f / 128.0f);
    float v = sq * (1.0f / 128.0f) - m * m;
    float inv = 1.0f / sqrtf(v + 1e-6f);
    float o0 = g[lane]      * (x0 - m) * inv + bl[lane];
    float o1 = g[lane + 64] * (x1 - m) * inv + bl[lane + 64];
    outp[lane] = o0; outp[lane + 64] = o1;
    outb[lane] = f2b(o0); outb[lane + 64] = f2b(o1);
}

// ---------------- weight transpose+cast: W[K][N] fp32 -> Wt[N][K] bf16 ----------------
__global__ void transpose_cast(const float* __restrict__ in, unsigned short* __restrict__ out,
                               int K, int N) {
    int t = blockIdx.x * blockDim.x + threadIdx.x;
    if (t >= K * N) return;
    int n = t / K, k = t - n * K;
    out[t] = f2b(in[(size_t)k * N + n]);
}

// ---------------- CSR build (once per call) ----------------
__global__ void zero_int_kernel(int* __restrict__ p, int n) {
    int i = blockIdx.x * blockDim.x + threadIdx.x;
    if (i < n) p[i] = 0;
}
__global__ void hist_kernel(const int* __restrict__ tgt_c, const int* __restrict__ tgt_v,
                            int* __restrict__ cnt_c, int* __restrict__ cnt_v) {
    int e = blockIdx.x * blockDim.x + threadIdx.x;
    if (e >= NE) return;
    atomicAdd(&cnt_c[tgt_c[e]], 1);
    atomicAdd(&cnt_v[tgt_v[e]], 1);
}
__launch_bounds__(1024)
__global__ void scan_kernel(const int* __restrict__ cnt, int* __restrict__ rowptr, int n) {
    __shared__ int part[1024];
    int t = threadIdx.x;
    int chunk = (n + 1023) >> 10;
    int base = t * chunk;
    int s = 0;
    for (int i = 0; i < chunk; i++) { int idx = base + i; if (idx < n) s += cnt[idx]; }
    part[t] = s;
    __syncthreads();
    for (int off = 1; off < 1024; off <<= 1) {
        int u = (t >= off) ? part[t - off] : 0;
        __syncthreads();
        part[t] += u;
        __syncthreads();
    }
    int run = part[t] - s;  // exclusive offset
    for (int i = 0; i < chunk; i++) {
        int idx = base + i;
        if (idx < n) { rowptr[idx] = run; run += cnt[idx]; }
    }
    if (t == 0) rowptr[n] = part[1023];
}
__global__ void fill_kernel(const int* __restrict__ tgt_c, const int* __restrict__ tgt_v,
                            const int* __restrict__ rp_c, const int* __restrict__ rp_v,
                            int* __restrict__ fill_c, int* __restrict__ fill_v,
                            int* __restrict__ eid_c, int* __restrict__ eid_v) {
    int e = blockIdx.x * blockDim.x + threadIdx.x;
    if (e >= NE) return;
    int tc = tgt_c[e];
    eid_c[rp_c[tc] + atomicAdd(&fill_c[tc], 1)] = e;
    int tv = tgt_v[e];
    eid_v[rp_v[tv] + atomicAdd(&fill_v[tv], 1)] = e;
}

// ---------------- bf16 MFMA GEMM ----------------
// out[M x Ntot] = act( [A1(idx1) | A2(idx2)]_bf16 @ W_bf16 + bias ), W given pre-transposed
// Wt[Ntot][K]. BM=64, BN=128 (grid.y tiles Ntot), BK=32, 256 thr = 4 waves of 32x64.
template<bool GATHER, bool HAS_A2, bool DO_ELU, bool OUT_BF16>
__launch_bounds__(256)
__global__ void mfma_gemm(const unsigned short* __restrict__ A1,
                          const unsigned short* __restrict__ A2,
                          const int* __restrict__ idx1, const int* __restrict__ idx2,
                          const unsigned short* __restrict__ Wt, int K,
                          const float* __restrict__ bias,
                          void* __restrict__ out, int ldOut, int M) {
    __shared__ unsigned short sA[64 * 40];    // [m][k] stride 40 (bank-uniform b128)
    __shared__ unsigned short sB[128 * 40];   // [n][k] stride 40
    const int tid = threadIdx.x;
    const int blockM = blockIdx.x * 64;
    const int n0b = blockIdx.y * 128;
    const int lane = tid & 63, wave = tid >> 6;
    const int quad = lane >> 4, l16 = lane & 15;
    const int wm = (wave >> 1) * 32, wn = (wave & 1) * 64;

    // staging roles (A): row r, 16B chunk ch
    const int r = tid >> 2, ch = tid & 3;
    int gmc = blockM + r; if (gmc >= M) gmc = M - 1;
    const int ia1 = GATHER ? idx1[gmc] : gmc;
    const int ia2 = HAS_A2 ? (GATHER ? idx2[gmc] : gmc) : 0;

    f4v acc[2][4];
    #pragma unroll
    for (int mt = 0; mt < 2; mt++)
        #pragma unroll
        for (int nt = 0; nt < 4; nt++) acc[mt][nt] = (f4v){0.f, 0.f, 0.f, 0.f};

    const int nsteps = K >> 5;
    for (int kt = 0; kt < nsteps; kt++) {
        const int kk = kt << 5;
        // stage A: 64 rows x 32 bf16
        {
            int kglob = kk + ch * 8;
            const unsigned short* src;
            if (HAS_A2 && kglob >= 128) src = A2 + (size_t)ia2 * Hdim + (kglob - 128);
            else                        src = A1 + (size_t)ia1 * Hdim + kglob;
            s8v v = *(const s8v*)src;
            *(s8v*)&sA[r * 40 + ch * 8] = v;
        }
        // stage B: 128 n-rows x 32 bf16 of Wt (2 passes)
        #pragma unroll
        for (int p = 0; p < 2; p++) {
            int n = (tid >> 2) + p * 64;
            s8v w = *(const s8v*)&Wt[(size_t)(n0b + n) * K + kk + ch * 8];
            *(s8v*)&sB[n * 40 + ch * 8] = w;
        }
        __syncthreads();
        s8v a[2], b[4];
        #pragma unroll
        for (int mt = 0; mt < 2; mt++)
            a[mt] = *(const s8v*)&sA[(wm + mt * 16 + l16) * 40 + quad * 8];
        #pragma unroll
        for (int nt = 0; nt < 4; nt++)
            b[nt] = *(const s8v*)&sB[(wn + nt * 16 + l16) * 40 + quad * 8];
        #pragma unroll
        for (int mt = 0; mt < 2; mt++)
            #pragma unroll
            for (int nt = 0; nt < 4; nt++)
                acc[mt][nt] = __builtin_amdgcn_mfma_f32_16x16x32_bf16(a[mt], b[nt], acc[mt][nt], 0, 0, 0);
        __syncthreads();
    }

    // epilogue: D row = quad*4 + reg, col = l16
    #pragma unroll
    for (int mt = 0; mt < 2; mt++) {
        #pragma unroll
        for (int reg = 0; reg < 4; reg++) {
            int mg = blockM + wm + mt * 16 + quad * 4 + reg;
            if (mg >= M) continue;
            #pragma unroll
            for (int nt = 0; nt < 4; nt++) {
                int nl = wn + nt * 16 + l16;
                float v = acc[mt][nt][reg] + bias[n0b + nl];
                if (DO_ELU) v = elu_f(v);
                if (OUT_BF16)
                    ((unsigned short*)out)[(size_t)mg * ldOut + n0b + nl] = f2b(v);
                else
                    ((float*)out)[(size_t)mg * ldOut + n0b + nl] = v;
            }
        }
    }
}

// ---------------- CSR gather-sum: agg[n][:] = sum over incident edges of msg[e][:] ----------------
__global__ void agg_kernel(const unsigned short* __restrict__ msg,
                           const int* __restrict__ rowptr, const int* __restrict__ eid,
                           unsigned short* __restrict__ agg) {
    int n = blockIdx.x;
    int t = threadIdx.x;  // 128 = one column each
    int b = rowptr[n], e = rowptr[n + 1];
    float s = 0.0f;
    for (int j = b; j < e; j++)
        s += b2f(msg[(size_t)eid[j] * Hdim + t]);
    agg[(size_t)n * Hdim + t] = f2b(s);
}

// ---------------- GRU gates (reset_after, order z,r,h); writes fp32 h + bf16 mirror ----------------
__global__ void gate_kernel(const float* __restrict__ xa, const float* __restrict__ ha,
                            float* __restrict__ h, unsigned short* __restrict__ hb, int N) {
    int g = blockIdx.x * blockDim.x + threadIdx.x;
    if (g >= N * Hdim) return;
    int i = g >> 7, t = g & 127;
    const float* xr = xa + (size_t)i * 384;
    const float* hr = ha + (size_t)i * 384;
    float z  = 1.0f / (1.0f + expf(-(xr[t] + hr[t])));
    float rr = 1.0f / (1.0f + expf(-(xr[128 + t] + hr[128 + t])));
    float hh = tanhf(xr[256 + t] + rr * hr[256 + t]);
    float hn = z * h[g] + (1.0f - z) * hh;
    h[g] = hn;
    hb[g] = f2b(hn);
}

// ---------------- final: out[i] = dot(hv[i], Wf) + bf ----------------
__global__ void final_kernel(const float* __restrict__ hv, const float* __restrict__ Wf,
                             const float* __restrict__ bf, float* __restrict__ out) {
    int node = blockIdx.x * 4 + (threadIdx.x >> 6);
    int lane = threadIdx.x & 63;
    const float* row = hv + (size_t)node * Hdim;
    float s = row[lane] * Wf[lane] + row[lane + 64] * Wf[lane + 64];
    #pragma unroll
    for (int off = 32; off > 0; off >>= 1) s += __shfl_xor(s, off);
    if (lane == 0) out[node] = s + bf[0];
}

extern "C" void kernel_launch(void* const* d_in, const int* in_sizes, int n_in,
                              void* d_out, int out_size, void* d_ws, size_t ws_size,
                              hipStream_t stream) {
    const float* cf      = (const float*)d_in[0];
    const float* vf      = (const float*)d_in[1];
    const int*   c2v_src = (const int*)d_in[2];
    const int*   c2v_tgt = (const int*)d_in[3];
    const int*   v2c_src = (const int*)d_in[4];
    const int*   v2c_tgt = (const int*)d_in[5];
    const float* Wc_in   = (const float*)d_in[6];
    const float* bc_in   = (const float*)d_in[7];
    const float* Wv_in   = (const float*)d_in[8];
    const float* bv_in   = (const float*)d_in[9];
    const float* gc_ln   = (const float*)d_in[10];
    const float* bc_ln   = (const float*)d_in[11];
    const float* gv_ln   = (const float*)d_in[12];
    const float* bv_ln   = (const float*)d_in[13];
    const float* Wmsg_c  = (const float*)d_in[14];
    const float* bmsg_c  = (const float*)d_in[15];
    const float* Wmsg_v  = (const float*)d_in[16];
    const float* bmsg_v  = (const float*)d_in[17];
    const float* Wns_c   = (const float*)d_in[18];
    const float* bns_c   = (const float*)d_in[19];
    const float* Wns_v   = (const float*)d_in[20];
    const float* bns_v   = (const float*)d_in[21];
    const float* Wg_c    = (const float*)d_in[22];
    const float* Ug_c    = (const float*)d_in[23];
    const float* bg_c    = (const float*)d_in[24];
    const float* Wg_v    = (const float*)d_in[25];
    const float* Ug_v    = (const float*)d_in[26];
    const float* bg_v    = (const float*)d_in[27];
    const float* Wf      = (const float*)d_in[28];
    const float* bf      = (const float*)d_in[29];
    float* out = (float*)d_out;

    // ---- workspace carve (all 256B-aligned) ----
    char* p = (char*)d_ws;
    #define CARVE(name, type, count) type* name = (type*)p; p += (((size_t)(count) * sizeof(type)) + 255) & ~(size_t)255;
    CARVE(hc,    float, NCn * Hdim)          // fp32 master states
    CARVE(hv,    float, NVn * Hdim)
    CARVE(U,     float, 12288000)            // union: msg bf16 [E,128]  |  xa/ha fp32 [NV,384] x2
    CARVE(hc_b,  unsigned short, NCn * Hdim) // bf16 mirrors
    CARVE(hv_b,  unsigned short, NVn * Hdim)
    CARVE(agg_c, unsigned short, NCn * Hdim)
    CARVE(agg_v, unsigned short, NVn * Hdim)
    CARVE(upd_c, unsigned short, NCn * Hdim)
    CARVE(upd_v, unsigned short, NVn * Hdim)
    CARVE(WTmsg_c, unsigned short, 128 * 256)  // Wt[N][K] bf16
    CARVE(WTmsg_v, unsigned short, 128 * 256)
    CARVE(WTns_c,  unsigned short, 128 * 256)
    CARVE(WTns_v,  unsigned short, 128 * 256)
    CARVE(WTg_c,   unsigned short, 384 * 128)
    CARVE(UTg_c,   unsigned short, 384 * 128)
    CARVE(WTg_v,   unsigned short, 384 * 128)
    CARVE(UTg_v,   unsigned short, 384 * 128)
    CARVE(rp_c,  int, NCn + 8)
    CARVE(rp_v,  int, NVn + 8)
    CARVE(eid_c, int, NE)
    CARVE(eid_v, int, NE)
    CARVE(cnts,  int, 48000)                 // cnt_c | cnt_v | fill_c | fill_v contiguous
    #undef CARVE
    int* cnt_c  = cnts;
    int* cnt_v  = cnts + NCn;
    int* fill_c = cnts + NCn + NVn;
    int* fill_v = cnts + 2 * NCn + NVn;
    unsigned short* msg = (unsigned short*)U;
    float* xa = U;
    float* ha = U + 6144000;

    // ---- once-per-call prep ----
    transpose_cast<<<(256 * 128 + 255) / 256, 256, 0, stream>>>(Wmsg_c, WTmsg_c, 256, 128);
    transpose_cast<<<(256 * 128 + 255) / 256, 256, 0, stream>>>(Wmsg_v, WTmsg_v, 256, 128);
    transpose_cast<<<(256 * 128 + 255) / 256, 256, 0, stream>>>(Wns_c,  WTns_c,  256, 128);
    transpose_cast<<<(256 * 128 + 255) / 256, 256, 0, stream>>>(Wns_v,  WTns_v,  256, 128);
    transpose_cast<<<(128 * 384 + 255) / 256, 256, 0, stream>>>(Wg_c, WTg_c, 128, 384);
    transpose_cast<<<(128 * 384 + 255) / 256, 256, 0, stream>>>(Ug_c, UTg_c, 128, 384);
    transpose_cast<<<(128 * 384 + 255) / 256, 256, 0, stream>>>(Wg_v, WTg_v, 128, 384);
    transpose_cast<<<(128 * 384 + 255) / 256, 256, 0, stream>>>(Ug_v, UTg_v, 128, 384);
    zero_int_kernel<<<(48000 + 255) / 256, 256, 0, stream>>>(cnts, 48000);
    hist_kernel<<<(NE + 255) / 256, 256, 0, stream>>>(v2c_tgt, c2v_tgt, cnt_c, cnt_v);
    scan_kernel<<<1, 1024, 0, stream>>>(cnt_c, rp_c, NCn);
    scan_kernel<<<1, 1024, 0, stream>>>(cnt_v, rp_v, NVn);
    fill_kernel<<<(NE + 255) / 256, 256, 0, stream>>>(v2c_tgt, c2v_tgt, rp_c, rp_v,
                                                      fill_c, fill_v, eid_c, eid_v);
    init_kernel<<<NCn + NVn, 64, 0, stream>>>(cf, vf, Wc_in, bc_in, Wv_in, bv_in,
                                              gc_ln, bc_ln, gv_ln, bv_ln, hc, hv, hc_b, hv_b);

    const int gridE = (NE + 63) / 64;   // 938
    const int gridC = NCn / 64;         // 125
    const int gridV = NVn / 64;         // 250

    for (int it = 0; it < LITERS; it++) {
        // v->c messages -> dense msg, then CSR gather-sum into agg_c
        mfma_gemm<true, true, true, true><<<dim3(gridE, 1), 256, 0, stream>>>(
            hv_b, hc_b, v2c_src, v2c_tgt, WTmsg_c, 256, bmsg_c, msg, 128, NE);
        agg_kernel<<<NCn, 128, 0, stream>>>(msg, rp_c, eid_c, agg_c);
        // c->v messages (reuse msg buffer)
        mfma_gemm<true, true, true, true><<<dim3(gridE, 1), 256, 0, stream>>>(
            hc_b, hv_b, c2v_src, c2v_tgt, WTmsg_v, 256, bmsg_v, msg, 128, NE);
        agg_kernel<<<NVn, 128, 0, stream>>>(msg, rp_v, eid_v, agg_v);

        // next-state: elu(concat(h, agg) @ Wns + b) -> upd (bf16)
        mfma_gemm<false, true, true, true><<<dim3(gridC, 1), 256, 0, stream>>>(
            hc_b, agg_c, nullptr, nullptr, WTns_c, 256, bns_c, upd_c, 128, NCn);
        mfma_gemm<false, true, true, true><<<dim3(gridV, 1), 256, 0, stream>>>(
            hv_b, agg_v, nullptr, nullptr, WTns_v, 256, bns_v, upd_v, 128, NVn);

        // GRU c (msg buffer dead now; xa/ha reuse U)
        mfma_gemm<false, false, false, false><<<dim3(gridC, 3), 256, 0, stream>>>(
            upd_c, nullptr, nullptr, nullptr, WTg_c, 128, bg_c, xa, 384, NCn);
        mfma_gemm<false, false, false, false><<<dim3(gridC, 3), 256, 0, stream>>>(
            hc_b, nullptr, nullptr, nullptr, UTg_c, 128, bg_c + 384, ha, 384, NCn);
        gate_kernel<<<(NCn * Hdim) / 256, 256, 0, stream>>>(xa, ha, hc, hc_b, NCn);

        // GRU v
        mfma_gemm<false, false, false, false><<<dim3(gridV, 3), 256, 0, stream>>>(
            upd_v, nullptr, nullptr, nullptr, WTg_v, 128, bg_v, xa, 384, NVn);
        mfma_gemm<false, false, false, false><<<dim3(gridV, 3), 256, 0, stream>>>(
            hv_b, nullptr, nullptr, nullptr, UTg_v, 128, bg_v + 384, ha, 384, NVn);
        gate_kernel<<<(NVn * Hdim) / 256, 256, 0, stream>>>(xa, ha, hv, hv_b, NVn);
    }

    final_kernel<<<NVn / 4, 256, 0, stream>>>(hv, Wf, bf, out);
}

// Round 3
// 1309.507 us; speedup vs baseline: 3.3499x; 1.1369x over previous
//
#include <hip/hip_runtime.h>
#include <hip/hip_bf16.h>
#include <math.h>

#define Hdim 128
#define NCn  8000
#define NVn  16000
#define NE   60000
#define LITERS 10

typedef __attribute__((ext_vector_type(8))) short s8v;   // 8 x bf16 (4 VGPRs)
typedef __attribute__((ext_vector_type(4))) float f4v;   // MFMA acc

__device__ __forceinline__ float elu_f(float x) { return x > 0.0f ? x : (expf(x) - 1.0f); }
__device__ __forceinline__ float sigm_f(float x) { return 1.0f / (1.0f + expf(-x)); }
__device__ __forceinline__ unsigned short f2b(float x) {
    __hip_bfloat16 h = __float2bfloat16(x); return *(unsigned short*)&h;
}
__device__ __forceinline__ float b2f(unsigned short u) {
    __hip_bfloat16 h; *(unsigned short*)&h = u; return __bfloat162float(h);
}

// ---------------- init: h = LN(0.1*f*W_in + b_in), fp32 + bf16 mirror ----------------
__global__ void init_kernel(const float* __restrict__ cf, const float* __restrict__ vf,
                            const float* __restrict__ Wc, const float* __restrict__ bc,
                            const float* __restrict__ Wv, const float* __restrict__ bv,
                            const float* __restrict__ gc, const float* __restrict__ bcl,
                            const float* __restrict__ gv, const float* __restrict__ bvl,
                            float* __restrict__ hc, float* __restrict__ hv,
                            unsigned short* __restrict__ hcb, unsigned short* __restrict__ hvb) {
    int node = blockIdx.x;
    int lane = threadIdx.x;  // 64 threads, 2 elements each
    const float *Win, *bin, *g, *bl;
    float f;
    float* outp;
    unsigned short* outb;
    if (node < NCn) {
        f = cf[node]; Win = Wc; bin = bc; g = gc; bl = bcl;
        outp = hc + (size_t)node * Hdim; outb = hcb + (size_t)node * Hdim;
    } else {
        int n2 = node - NCn;
        f = vf[n2]; Win = Wv; bin = bv; g = gv; bl = bvl;
        outp = hv + (size_t)n2 * Hdim; outb = hvb + (size_t)n2 * Hdim;
    }
    f *= 0.1f;
    float x0 = f * Win[lane] + bin[lane];
    float x1 = f * Win[lane + 64] + bin[lane + 64];
    float s = x0 + x1;
    float sq = x0 * x0 + x1 * x1;
    #pragma unroll
    for (int off = 32; off > 0; off >>= 1) {
        s += __shfl_xor(s, off);
        sq += __shfl_xor(sq, off);
    }
    float m = s * (1.0f / 128.0f);
    float v = sq * (1.0f / 128.0f) - m * m;
    float inv = 1.0f / sqrtf(v + 1e-6f);
    float o0 = g[lane]      * (x0 - m) * inv + bl[lane];
    float o1 = g[lane + 64] * (x1 - m) * inv + bl[lane + 64];
    outp[lane] = o0; outp[lane + 64] = o1;
    outb[lane] = f2b(o0); outb[lane + 64] = f2b(o1);
}

// ---------------- weight transpose+cast: W[K][N] fp32 -> Wt[N][K] bf16 ----------------
__global__ void transpose_cast(const float* __restrict__ in, unsigned short* __restrict__ out,
                               int K, int N) {
    int t = blockIdx.x * blockDim.x + threadIdx.x;
    if (t >= K * N) return;
    int n = t / K, k = t - n * K;
    out[t] = f2b(in[(size_t)k * N + n]);
}

// GRU weight prep: Wcat[n][k] (n<384, K=256): k<128 -> Ug[k][n] (recurrent vs hb),
// k>=128 -> Wg[k-128][n] (input vs upd). Uh[n][k] (n<128, K=128) = Ug[k][256+n].
__global__ void prep_gru_w(const float* __restrict__ Wg, const float* __restrict__ Ug,
                           unsigned short* __restrict__ Wcat, unsigned short* __restrict__ Uh) {
    int idx = blockIdx.x * blockDim.x + threadIdx.x;
    if (idx < 384 * 256) {
        int n = idx >> 8, k = idx & 255;
        float v = (k < 128) ? Ug[(size_t)k * 384 + n] : Wg[(size_t)(k - 128) * 384 + n];
        Wcat[idx] = f2b(v);
    } else if (idx < 384 * 256 + 128 * 128) {
        int j = idx - 384 * 256;
        int n = j >> 7, k = j & 127;
        Uh[j] = f2b(Ug[(size_t)k * 384 + 256 + n]);
    }
}

// ---------------- CSR build (once per call) ----------------
__global__ void zero_int_kernel(int* __restrict__ p, int n) {
    int i = blockIdx.x * blockDim.x + threadIdx.x;
    if (i < n) p[i] = 0;
}
__global__ void hist_kernel(const int* __restrict__ tgt_c, const int* __restrict__ tgt_v,
                            int* __restrict__ cnt_c, int* __restrict__ cnt_v) {
    int e = blockIdx.x * blockDim.x + threadIdx.x;
    if (e >= NE) return;
    atomicAdd(&cnt_c[tgt_c[e]], 1);
    atomicAdd(&cnt_v[tgt_v[e]], 1);
}
__launch_bounds__(1024)
__global__ void scan_kernel(const int* __restrict__ cnt, int* __restrict__ rowptr, int n) {
    __shared__ int part[1024];
    int t = threadIdx.x;
    int chunk = (n + 1023) >> 10;
    int base = t * chunk;
    int s = 0;
    for (int i = 0; i < chunk; i++) { int idx = base + i; if (idx < n) s += cnt[idx]; }
    part[t] = s;
    __syncthreads();
    for (int off = 1; off < 1024; off <<= 1) {
        int u = (t >= off) ? part[t - off] : 0;
        __syncthreads();
        part[t] += u;
        __syncthreads();
    }
    int run = part[t] - s;  // exclusive offset
    for (int i = 0; i < chunk; i++) {
        int idx = base + i;
        if (idx < n) { rowptr[idx] = run; run += cnt[idx]; }
    }
    if (t == 0) rowptr[n] = part[1023];
}
__global__ void fill_kernel(const int* __restrict__ tgt_c, const int* __restrict__ tgt_v,
                            const int* __restrict__ rp_c, const int* __restrict__ rp_v,
                            int* __restrict__ fill_c, int* __restrict__ fill_v,
                            int* __restrict__ eid_c, int* __restrict__ eid_v) {
    int e = blockIdx.x * blockDim.x + threadIdx.x;
    if (e >= NE) return;
    int tc = tgt_c[e];
    eid_c[rp_c[tc] + atomicAdd(&fill_c[tc], 1)] = e;
    int tv = tgt_v[e];
    eid_v[rp_v[tv] + atomicAdd(&fill_v[tv], 1)] = e;
}

// ---------------- bf16 MFMA edge GEMM (messages) ----------------
// msg[e][:] = elu( [A1(idx1[e]) | A2(idx2[e])] @ Wt + bias ). BM=64, BK=32, N=128.
__launch_bounds__(256)
__global__ void edge_gemm(const unsigned short* __restrict__ A1,
                          const unsigned short* __restrict__ A2,
                          const int* __restrict__ idx1, const int* __restrict__ idx2,
                          const unsigned short* __restrict__ Wt,
                          const float* __restrict__ bias,
                          unsigned short* __restrict__ out, int M) {
    __shared__ unsigned short sA[64 * 40];
    __shared__ unsigned short sB[128 * 40];
    const int tid = threadIdx.x;
    const int blockM = blockIdx.x * 64;
    const int lane = tid & 63, wave = tid >> 6;
    const int quad = lane >> 4, l16 = lane & 15;
    const int wm = (wave >> 1) * 32, wn = (wave & 1) * 64;

    const int r = tid >> 2, ch = tid & 3;
    int gmc = blockM + r; if (gmc >= M) gmc = M - 1;
    const int ia1 = idx1[gmc];
    const int ia2 = idx2[gmc];

    f4v acc[2][4];
    #pragma unroll
    for (int mt = 0; mt < 2; mt++)
        #pragma unroll
        for (int nt = 0; nt < 4; nt++) acc[mt][nt] = (f4v){0.f, 0.f, 0.f, 0.f};

    for (int kt = 0; kt < 8; kt++) {
        const int kk = kt << 5;
        {
            int kglob = kk + ch * 8;
            const unsigned short* src = (kglob >= 128)
                ? A2 + (size_t)ia2 * Hdim + (kglob - 128)
                : A1 + (size_t)ia1 * Hdim + kglob;
            *(s8v*)&sA[r * 40 + ch * 8] = *(const s8v*)src;
        }
        #pragma unroll
        for (int p = 0; p < 2; p++) {
            int n = (tid >> 2) + p * 64;
            *(s8v*)&sB[n * 40 + ch * 8] = *(const s8v*)&Wt[(size_t)n * 256 + kk + ch * 8];
        }
        __syncthreads();
        s8v a[2], b[4];
        #pragma unroll
        for (int mt = 0; mt < 2; mt++)
            a[mt] = *(const s8v*)&sA[(wm + mt * 16 + l16) * 40 + quad * 8];
        #pragma unroll
        for (int nt = 0; nt < 4; nt++)
            b[nt] = *(const s8v*)&sB[(wn + nt * 16 + l16) * 40 + quad * 8];
        #pragma unroll
        for (int mt = 0; mt < 2; mt++)
            #pragma unroll
            for (int nt = 0; nt < 4; nt++)
                acc[mt][nt] = __builtin_amdgcn_mfma_f32_16x16x32_bf16(a[mt], b[nt], acc[mt][nt], 0, 0, 0);
        __syncthreads();
    }

    #pragma unroll
    for (int mt = 0; mt < 2; mt++) {
        #pragma unroll
        for (int reg = 0; reg < 4; reg++) {
            int mg = blockM + wm + mt * 16 + quad * 4 + reg;
            if (mg >= M) continue;
            #pragma unroll
            for (int nt = 0; nt < 4; nt++) {
                int nl = wn + nt * 16 + l16;
                float v = elu_f(acc[mt][nt][reg] + bias[nl]);
                out[(size_t)mg * Hdim + nl] = f2b(v);
            }
        }
    }
}

// ---------------- CSR gather-sum: agg[n][:] = sum over incident edges ----------------
__global__ void agg_kernel(const unsigned short* __restrict__ msg,
                           const int* __restrict__ rowptr, const int* __restrict__ eid,
                           unsigned short* __restrict__ agg) {
    int n = blockIdx.x;
    int t = threadIdx.x;  // 128 = one column each
    int b = rowptr[n], e = rowptr[n + 1];
    float s = 0.0f;
    for (int j = b; j < e; j++)
        s += b2f(msg[(size_t)eid[j] * Hdim + t]);
    agg[(size_t)n * Hdim + t] = f2b(s);
}

// ---------------- fused node update: ns-GEMM + GRU (both GEMMs) + gates ----------------
// Phase 1: upd = elu([hb | agg] @ WTns^T + bns)   (kept in LDS, bf16)
// Phase 2: S   = [hb | upd] @ Wcat^T               (= xa + ha, no bias, [64,384])
//          Hh  = hb @ Uh^T                          (= ha_h w/o bias, [64,128])
// Gates:   z = sig(S_z + bz0+bz1), r = sig(S_r + br0+br1)
//          xa_h = S_h - Hh + b0_h ; ha_h = Hh + b1_h ; hh = tanh(xa_h + r*ha_h)
//          h = z*h_old + (1-z)*hh        (fp32 master, bf16 mirror)
// Requires M % 64 == 0 (8000, 16000 both are).
__launch_bounds__(256)
__global__ void node_update(unsigned short* __restrict__ hb,
                            const unsigned short* __restrict__ agg,
                            float* __restrict__ h,
                            const unsigned short* __restrict__ WTns,
                            const float* __restrict__ bns,
                            const unsigned short* __restrict__ Wcat,
                            const unsigned short* __restrict__ Uh,
                            const float* __restrict__ bg) {
    __shared__ unsigned short sA[64 * 264];   // [row][k] K=256, stride 264
    __shared__ unsigned short sB[384 * 40];   // staged weight k-slices, stride 40
    const int tid = threadIdx.x;
    const int blockM = blockIdx.x * 64;
    const int lane = tid & 63, wave = tid >> 6;
    const int quad = lane >> 4, l16 = lane & 15;
    const int wm16 = wave * 16;               // each wave owns a 16-row strip
    const int r = tid >> 2, ch = tid & 3;

    // ---- stage A = [hb | agg] for this block's 64 rows ----
    #pragma unroll
    for (int j = 0; j < 8; j++) {
        int k = ch * 8 + j * 32;
        const unsigned short* src = (k < 128)
            ? hb  + (size_t)(blockM + r) * Hdim + k
            : agg + (size_t)(blockM + r) * Hdim + (k - 128);
        *(s8v*)&sA[r * 264 + k] = *(const s8v*)src;
    }

    // ---- phase 1: ns GEMM, 8 col-tiles per wave strip ----
    f4v accN[8];
    #pragma unroll
    for (int nt = 0; nt < 8; nt++) accN[nt] = (f4v){0.f, 0.f, 0.f, 0.f};
    for (int kt = 0; kt < 8; kt++) {
        #pragma unroll
        for (int p = 0; p < 2; p++) {
            int n = (tid >> 2) + p * 64;
            *(s8v*)&sB[n * 40 + ch * 8] = *(const s8v*)&WTns[(size_t)n * 256 + kt * 32 + ch * 8];
        }
        __syncthreads();
        s8v a = *(const s8v*)&sA[(wm16 + l16) * 264 + kt * 32 + quad * 8];
        #pragma unroll
        for (int nt = 0; nt < 8; nt++) {
            s8v b = *(const s8v*)&sB[(nt * 16 + l16) * 40 + quad * 8];
            accN[nt] = __builtin_amdgcn_mfma_f32_16x16x32_bf16(a, b, accN[nt], 0, 0, 0);
        }
        __syncthreads();
    }
    // write upd into sA cols [128:256) (overwrites agg; all reads of it are done)
    #pragma unroll
    for (int nt = 0; nt < 8; nt++) {
        #pragma unroll
        for (int reg = 0; reg < 4; reg++) {
            int row = wm16 + quad * 4 + reg;
            int col = nt * 16 + l16;
            float v = elu_f(accN[nt][reg] + bns[col]);
            sA[row * 264 + 128 + col] = f2b(v);
        }
    }
    // (visibility of these writes to other waves is guaranteed by the sync inside the next loop)

    // ---- phase 2a: S = [hb | upd] @ Wcat^T  (24 col-tiles per strip) ----
    f4v accS[24];
    #pragma unroll
    for (int nt = 0; nt < 24; nt++) accS[nt] = (f4v){0.f, 0.f, 0.f, 0.f};
    for (int kt = 0; kt < 8; kt++) {
        #pragma unroll
        for (int p = 0; p < 6; p++) {
            int n = (tid >> 2) + p * 64;
            *(s8v*)&sB[n * 40 + ch * 8] = *(const s8v*)&Wcat[(size_t)n * 256 + kt * 32 + ch * 8];
        }
        __syncthreads();
        s8v a = *(const s8v*)&sA[(wm16 + l16) * 264 + kt * 32 + quad * 8];
        #pragma unroll
        for (int nt = 0; nt < 24; nt++) {
            s8v b = *(const s8v*)&sB[(nt * 16 + l16) * 40 + quad * 8];
            accS[nt] = __builtin_amdgcn_mfma_f32_16x16x32_bf16(a, b, accS[nt], 0, 0, 0);
        }
        __syncthreads();
    }

    // ---- phase 2b: Hh = hb @ Uh^T  (8 col-tiles, K=128 = sA cols [0:128)) ----
    f4v accH[8];
    #pragma unroll
    for (int nt = 0; nt < 8; nt++) accH[nt] = (f4v){0.f, 0.f, 0.f, 0.f};
    for (int kt = 0; kt < 4; kt++) {
        #pragma unroll
        for (int p = 0; p < 2; p++) {
            int n = (tid >> 2) + p * 64;
            *(s8v*)&sB[n * 40 + ch * 8] = *(const s8v*)&Uh[(size_t)n * 128 + kt * 32 + ch * 8];
        }
        __syncthreads();
        s8v a = *(const s8v*)&sA[(wm16 + l16) * 264 + kt * 32 + quad * 8];
        #pragma unroll
        for (int nt = 0; nt < 8; nt++) {
            s8v b = *(const s8v*)&sB[(nt * 16 + l16) * 40 + quad * 8];
            accH[nt] = __builtin_amdgcn_mfma_f32_16x16x32_bf16(a, b, accH[nt], 0, 0, 0);
        }
        __syncthreads();
    }

    // ---- gates (all per-lane: cols t, 128+t, 256+t share l16) ----
    #pragma unroll
    for (int j = 0; j < 8; j++) {
        int t = j * 16 + l16;
        float bz = bg[t]       + bg[384 + t];
        float br = bg[128 + t] + bg[512 + t];
        float b0h = bg[256 + t];
        float b1h = bg[640 + t];
        #pragma unroll
        for (int reg = 0; reg < 4; reg++) {
            int row = blockM + wm16 + quad * 4 + reg;
            float Sz = accS[j][reg]      + bz;
            float Sr = accS[8 + j][reg]  + br;
            float Sh = accS[16 + j][reg];
            float Hh = accH[j][reg];
            float z = sigm_f(Sz);
            float rr = sigm_f(Sr);
            float hh = tanhf((Sh - Hh + b0h) + rr * (Hh + b1h));
            float hold = h[(size_t)row * Hdim + t];
            float hn = z * hold + (1.0f - z) * hh;
            h[(size_t)row * Hdim + t] = hn;
            hb[(size_t)row * Hdim + t] = f2b(hn);
        }
    }
}

// ---------------- final: out[i] = dot(hv[i], Wf) + bf ----------------
__global__ void final_kernel(const float* __restrict__ hv, const float* __restrict__ Wf,
                             const float* __restrict__ bf, float* __restrict__ out) {
    int node = blockIdx.x * 4 + (threadIdx.x >> 6);
    int lane = threadIdx.x & 63;
    const float* row = hv + (size_t)node * Hdim;
    float s = row[lane] * Wf[lane] + row[lane + 64] * Wf[lane + 64];
    #pragma unroll
    for (int off = 32; off > 0; off >>= 1) s += __shfl_xor(s, off);
    if (lane == 0) out[node] = s + bf[0];
}

extern "C" void kernel_launch(void* const* d_in, const int* in_sizes, int n_in,
                              void* d_out, int out_size, void* d_ws, size_t ws_size,
                              hipStream_t stream) {
    const float* cf      = (const float*)d_in[0];
    const float* vf      = (const float*)d_in[1];
    const int*   c2v_src = (const int*)d_in[2];
    const int*   c2v_tgt = (const int*)d_in[3];
    const int*   v2c_src = (const int*)d_in[4];
    const int*   v2c_tgt = (const int*)d_in[5];
    const float* Wc_in   = (const float*)d_in[6];
    const float* bc_in   = (const float*)d_in[7];
    const float* Wv_in   = (const float*)d_in[8];
    const float* bv_in   = (const float*)d_in[9];
    const float* gc_ln   = (const float*)d_in[10];
    const float* bc_ln   = (const float*)d_in[11];
    const float* gv_ln   = (const float*)d_in[12];
    const float* bv_ln   = (const float*)d_in[13];
    const float* Wmsg_c  = (const float*)d_in[14];
    const float* bmsg_c  = (const float*)d_in[15];
    const float* Wmsg_v  = (const float*)d_in[16];
    const float* bmsg_v  = (const float*)d_in[17];
    const float* Wns_c   = (const float*)d_in[18];
    const float* bns_c   = (const float*)d_in[19];
    const float* Wns_v   = (const float*)d_in[20];
    const float* bns_v   = (const float*)d_in[21];
    const float* Wg_c    = (const float*)d_in[22];
    const float* Ug_c    = (const float*)d_in[23];
    const float* bg_c    = (const float*)d_in[24];
    const float* Wg_v    = (const float*)d_in[25];
    const float* Ug_v    = (const float*)d_in[26];
    const float* bg_v    = (const float*)d_in[27];
    const float* Wf      = (const float*)d_in[28];
    const float* bf      = (const float*)d_in[29];
    float* out = (float*)d_out;

    // ---- workspace carve (256B-aligned) ----
    char* p = (char*)d_ws;
    #define CARVE(name, type, count) type* name = (type*)p; p += (((size_t)(count) * sizeof(type)) + 255) & ~(size_t)255;
    CARVE(hc,    float, NCn * Hdim)
    CARVE(hv,    float, NVn * Hdim)
    CARVE(msg,   unsigned short, NE * Hdim)
    CARVE(hc_b,  unsigned short, NCn * Hdim)
    CARVE(hv_b,  unsigned short, NVn * Hdim)
    CARVE(agg_c, unsigned short, NCn * Hdim)
    CARVE(agg_v, unsigned short, NVn * Hdim)
    CARVE(WTmsg_c, unsigned short, 128 * 256)
    CARVE(WTmsg_v, unsigned short, 128 * 256)
    CARVE(WTns_c,  unsigned short, 128 * 256)
    CARVE(WTns_v,  unsigned short, 128 * 256)
    CARVE(Wcat_c,  unsigned short, 384 * 256)
    CARVE(Uh_c,    unsigned short, 128 * 128)
    CARVE(Wcat_v,  unsigned short, 384 * 256)
    CARVE(Uh_v,    unsigned short, 128 * 128)
    CARVE(rp_c,  int, NCn + 8)
    CARVE(rp_v,  int, NVn + 8)
    CARVE(eid_c, int, NE)
    CARVE(eid_v, int, NE)
    CARVE(cnts,  int, 48000)
    #undef CARVE
    int* cnt_c  = cnts;
    int* cnt_v  = cnts + NCn;
    int* fill_c = cnts + NCn + NVn;
    int* fill_v = cnts + 2 * NCn + NVn;

    // ---- once-per-call prep ----
    transpose_cast<<<(256 * 128 + 255) / 256, 256, 0, stream>>>(Wmsg_c, WTmsg_c, 256, 128);
    transpose_cast<<<(256 * 128 + 255) / 256, 256, 0, stream>>>(Wmsg_v, WTmsg_v, 256, 128);
    transpose_cast<<<(256 * 128 + 255) / 256, 256, 0, stream>>>(Wns_c,  WTns_c,  256, 128);
    transpose_cast<<<(256 * 128 + 255) / 256, 256, 0, stream>>>(Wns_v,  WTns_v,  256, 128);
    prep_gru_w<<<(384 * 256 + 128 * 128 + 255) / 256, 256, 0, stream>>>(Wg_c, Ug_c, Wcat_c, Uh_c);
    prep_gru_w<<<(384 * 256 + 128 * 128 + 255) / 256, 256, 0, stream>>>(Wg_v, Ug_v, Wcat_v, Uh_v);
    zero_int_kernel<<<(48000 + 255) / 256, 256, 0, stream>>>(cnts, 48000);
    hist_kernel<<<(NE + 255) / 256, 256, 0, stream>>>(v2c_tgt, c2v_tgt, cnt_c, cnt_v);
    scan_kernel<<<1, 1024, 0, stream>>>(cnt_c, rp_c, NCn);
    scan_kernel<<<1, 1024, 0, stream>>>(cnt_v, rp_v, NVn);
    fill_kernel<<<(NE + 255) / 256, 256, 0, stream>>>(v2c_tgt, c2v_tgt, rp_c, rp_v,
                                                      fill_c, fill_v, eid_c, eid_v);
    init_kernel<<<NCn + NVn, 64, 0, stream>>>(cf, vf, Wc_in, bc_in, Wv_in, bv_in,
                                              gc_ln, bc_ln, gv_ln, bv_ln, hc, hv, hc_b, hv_b);

    const int gridE = (NE + 63) / 64;   // 938

    for (int it = 0; it < LITERS; it++) {
        // v->c messages -> msg, CSR gather-sum -> agg_c
        edge_gemm<<<gridE, 256, 0, stream>>>(hv_b, hc_b, v2c_src, v2c_tgt, WTmsg_c, bmsg_c, msg, NE);
        agg_kernel<<<NCn, 128, 0, stream>>>(msg, rp_c, eid_c, agg_c);
        // c->v messages -> msg, -> agg_v
        edge_gemm<<<gridE, 256, 0, stream>>>(hc_b, hv_b, c2v_src, c2v_tgt, WTmsg_v, bmsg_v, msg, NE);
        agg_kernel<<<NVn, 128, 0, stream>>>(msg, rp_v, eid_v, agg_v);
        // fused next-state + GRU
        node_update<<<NCn / 64, 256, 0, stream>>>(hc_b, agg_c, hc, WTns_c, bns_c, Wcat_c, Uh_c, bg_c);
        node_update<<<NVn / 64, 256, 0, stream>>>(hv_b, agg_v, hv, WTns_v, bns_v, Wcat_v, Uh_v, bg_v);
    }

    final_kernel<<<NVn / 4, 256, 0, stream>>>(hv, Wf, bf, out);
}

// Round 4
// 1078.250 us; speedup vs baseline: 4.0684x; 1.2145x over previous
//
#include <hip/hip_runtime.h>
#include <hip/hip_bf16.h>
#include <math.h>

#define Hdim 128
#define NCn  8000
#define NVn  16000
#define NE   60000
#define LITERS 10

typedef __attribute__((ext_vector_type(8))) short s8v;   // 8 x bf16 (4 VGPRs)
typedef __attribute__((ext_vector_type(4))) float f4v;   // MFMA acc

__device__ __forceinline__ float elu_f(float x) { return x > 0.0f ? x : (expf(x) - 1.0f); }
__device__ __forceinline__ float sigm_f(float x) { return 1.0f / (1.0f + expf(-x)); }
__device__ __forceinline__ unsigned short f2b(float x) {
    __hip_bfloat16 h = __float2bfloat16(x); return *(unsigned short*)&h;
}
__device__ __forceinline__ float b2f(unsigned short u) {
    __hip_bfloat16 h; *(unsigned short*)&h = u; return __bfloat162float(h);
}

// ---------------- init: h = LN(0.1*f*W_in + b_in), fp32 + bf16 mirror ----------------
__global__ void init_kernel(const float* __restrict__ cf, const float* __restrict__ vf,
                            const float* __restrict__ Wc, const float* __restrict__ bc,
                            const float* __restrict__ Wv, const float* __restrict__ bv,
                            const float* __restrict__ gc, const float* __restrict__ bcl,
                            const float* __restrict__ gv, const float* __restrict__ bvl,
                            float* __restrict__ hc, float* __restrict__ hv,
                            unsigned short* __restrict__ hcb, unsigned short* __restrict__ hvb) {
    int node = blockIdx.x;
    int lane = threadIdx.x;  // 64 threads, 2 elements each
    const float *Win, *bin, *g, *bl;
    float f;
    float* outp;
    unsigned short* outb;
    if (node < NCn) {
        f = cf[node]; Win = Wc; bin = bc; g = gc; bl = bcl;
        outp = hc + (size_t)node * Hdim; outb = hcb + (size_t)node * Hdim;
    } else {
        int n2 = node - NCn;
        f = vf[n2]; Win = Wv; bin = bv; g = gv; bl = bvl;
        outp = hv + (size_t)n2 * Hdim; outb = hvb + (size_t)n2 * Hdim;
    }
    f *= 0.1f;
    float x0 = f * Win[lane] + bin[lane];
    float x1 = f * Win[lane + 64] + bin[lane + 64];
    float s = x0 + x1;
    float sq = x0 * x0 + x1 * x1;
    #pragma unroll
    for (int off = 32; off > 0; off >>= 1) {
        s += __shfl_xor(s, off);
        sq += __shfl_xor(sq, off);
    }
    float m = s * (1.0f / 128.0f);
    float v = sq * (1.0f / 128.0f) - m * m;
    float inv = 1.0f / sqrtf(v + 1e-6f);
    float o0 = g[lane]      * (x0 - m) * inv + bl[lane];
    float o1 = g[lane + 64] * (x1 - m) * inv + bl[lane + 64];
    outp[lane] = o0; outp[lane + 64] = o1;
    outb[lane] = f2b(o0); outb[lane + 64] = f2b(o1);
}

// ---------------- all weight prep in one kernel ----------------
// segs 0-3: Wt[N=128][K=256] <- transpose(W[256][128]) for Wmsg_c/Wmsg_v/Wns_c/Wns_v
// segs 4-5: GRU pack (c then v): Wcat[384][256] (k<128 from Ug, k>=128 from Wg), Uh[128][128]
__global__ void prep_weights(const float* __restrict__ Wmsg_c, const float* __restrict__ Wmsg_v,
                             const float* __restrict__ Wns_c,  const float* __restrict__ Wns_v,
                             const float* __restrict__ Wg_c, const float* __restrict__ Ug_c,
                             const float* __restrict__ Wg_v, const float* __restrict__ Ug_v,
                             unsigned short* __restrict__ WTmsg_c, unsigned short* __restrict__ WTmsg_v,
                             unsigned short* __restrict__ WTns_c,  unsigned short* __restrict__ WTns_v,
                             unsigned short* __restrict__ Wcat_c, unsigned short* __restrict__ Uh_c,
                             unsigned short* __restrict__ Wcat_v, unsigned short* __restrict__ Uh_v) {
    int idx = blockIdx.x * blockDim.x + threadIdx.x;
    const int TS = 128 * 256;
    const int GS = 384 * 256 + 128 * 128;
    if (idx < 4 * TS) {
        int seg = idx / TS, t = idx - seg * TS;
        const float* in = (seg == 0) ? Wmsg_c : (seg == 1) ? Wmsg_v : (seg == 2) ? Wns_c : Wns_v;
        unsigned short* out = (seg == 0) ? WTmsg_c : (seg == 1) ? WTmsg_v : (seg == 2) ? WTns_c : WTns_v;
        int n = t >> 8, k = t & 255;
        out[t] = f2b(in[(size_t)k * 128 + n]);
    } else if (idx < 4 * TS + 2 * GS) {
        int j = idx - 4 * TS;
        int seg = j / GS, t = j - seg * GS;
        const float* Wg = seg ? Wg_v : Wg_c;
        const float* Ug = seg ? Ug_v : Ug_c;
        unsigned short* Wcat = seg ? Wcat_v : Wcat_c;
        unsigned short* Uh = seg ? Uh_v : Uh_c;
        if (t < 384 * 256) {
            int n = t >> 8, k = t & 255;
            Wcat[t] = f2b((k < 128) ? Ug[(size_t)k * 384 + n] : Wg[(size_t)(k - 128) * 384 + n]);
        } else {
            int q = t - 384 * 256;
            int n = q >> 7, k = q & 127;
            Uh[q] = f2b(Ug[(size_t)k * 384 + 256 + n]);
        }
    }
}

// ---------------- CSR build (once per call) ----------------
__global__ void zero_int_kernel(int* __restrict__ p, int n) {
    int i = blockIdx.x * blockDim.x + threadIdx.x;
    if (i < n) p[i] = 0;
}
__global__ void hist_kernel(const int* __restrict__ tgt_c, const int* __restrict__ tgt_v,
                            int* __restrict__ cnt_c, int* __restrict__ cnt_v) {
    int e = blockIdx.x * blockDim.x + threadIdx.x;
    if (e >= NE) return;
    atomicAdd(&cnt_c[tgt_c[e]], 1);
    atomicAdd(&cnt_v[tgt_v[e]], 1);
}
__launch_bounds__(1024)
__global__ void scan_kernel(const int* __restrict__ cnt, int* __restrict__ rowptr, int n) {
    __shared__ int part[1024];
    int t = threadIdx.x;
    int chunk = (n + 1023) >> 10;
    int base = t * chunk;
    int s = 0;
    for (int i = 0; i < chunk; i++) { int idx = base + i; if (idx < n) s += cnt[idx]; }
    part[t] = s;
    __syncthreads();
    for (int off = 1; off < 1024; off <<= 1) {
        int u = (t >= off) ? part[t - off] : 0;
        __syncthreads();
        part[t] += u;
        __syncthreads();
    }
    int run = part[t] - s;  // exclusive offset
    for (int i = 0; i < chunk; i++) {
        int idx = base + i;
        if (idx < n) { rowptr[idx] = run; run += cnt[idx]; }
    }
    if (t == 0) rowptr[n] = part[1023];
}
__global__ void fill_kernel(const int* __restrict__ tgt_c, const int* __restrict__ tgt_v,
                            const int* __restrict__ rp_c, const int* __restrict__ rp_v,
                            int* __restrict__ fill_c, int* __restrict__ fill_v,
                            int* __restrict__ eid_c, int* __restrict__ eid_v) {
    int e = blockIdx.x * blockDim.x + threadIdx.x;
    if (e >= NE) return;
    int tc = tgt_c[e];
    eid_c[rp_c[tc] + atomicAdd(&fill_c[tc], 1)] = e;
    int tv = tgt_v[e];
    eid_v[rp_v[tv] + atomicAdd(&fill_v[tv], 1)] = e;
}

// ---------------- both edge GEMMs in one launch ----------------
// d=0: msg_vc[e] = elu([hv(v2c_src)|hc(v2c_tgt)] @ WTc + bc)
// d=1: msg_cv[e] = elu([hc(c2v_src)|hv(c2v_tgt)] @ WTv + bv)
__launch_bounds__(256)
__global__ void edge_gemm_dual(const unsigned short* __restrict__ hvb,
                               const unsigned short* __restrict__ hcb,
                               const int* __restrict__ v2c_src, const int* __restrict__ v2c_tgt,
                               const int* __restrict__ c2v_src, const int* __restrict__ c2v_tgt,
                               const unsigned short* __restrict__ WTc,
                               const unsigned short* __restrict__ WTv,
                               const float* __restrict__ bc, const float* __restrict__ bv,
                               unsigned short* __restrict__ msg_vc,
                               unsigned short* __restrict__ msg_cv,
                               int gridE) {
    __shared__ unsigned short sA[64 * 40];
    __shared__ unsigned short sB[128 * 40];
    const int tid = threadIdx.x;
    const int d = (blockIdx.x >= gridE) ? 1 : 0;
    const int blockM = (d ? (blockIdx.x - gridE) : blockIdx.x) * 64;
    const unsigned short* A1 = d ? hcb : hvb;
    const unsigned short* A2 = d ? hvb : hcb;
    const int* idx1 = d ? c2v_src : v2c_src;
    const int* idx2 = d ? c2v_tgt : v2c_tgt;
    const unsigned short* Wt = d ? WTv : WTc;
    const float* bias = d ? bv : bc;
    unsigned short* out = d ? msg_cv : msg_vc;

    const int lane = tid & 63, wave = tid >> 6;
    const int quad = lane >> 4, l16 = lane & 15;
    const int wm = (wave >> 1) * 32, wn = (wave & 1) * 64;
    const int r = tid >> 2, ch = tid & 3;
    int gmc = blockM + r; if (gmc >= NE) gmc = NE - 1;
    const int ia1 = idx1[gmc];
    const int ia2 = idx2[gmc];

    f4v acc[2][4];
    #pragma unroll
    for (int mt = 0; mt < 2; mt++)
        #pragma unroll
        for (int nt = 0; nt < 4; nt++) acc[mt][nt] = (f4v){0.f, 0.f, 0.f, 0.f};

    for (int kt = 0; kt < 8; kt++) {
        const int kk = kt << 5;
        {
            int kglob = kk + ch * 8;
            const unsigned short* src = (kglob >= 128)
                ? A2 + (size_t)ia2 * Hdim + (kglob - 128)
                : A1 + (size_t)ia1 * Hdim + kglob;
            *(s8v*)&sA[r * 40 + ch * 8] = *(const s8v*)src;
        }
        #pragma unroll
        for (int p = 0; p < 2; p++) {
            int n = (tid >> 2) + p * 64;
            *(s8v*)&sB[n * 40 + ch * 8] = *(const s8v*)&Wt[(size_t)n * 256 + kk + ch * 8];
        }
        __syncthreads();
        s8v a[2], b[4];
        #pragma unroll
        for (int mt = 0; mt < 2; mt++)
            a[mt] = *(const s8v*)&sA[(wm + mt * 16 + l16) * 40 + quad * 8];
        #pragma unroll
        for (int nt = 0; nt < 4; nt++)
            b[nt] = *(const s8v*)&sB[(wn + nt * 16 + l16) * 40 + quad * 8];
        #pragma unroll
        for (int mt = 0; mt < 2; mt++)
            #pragma unroll
            for (int nt = 0; nt < 4; nt++)
                acc[mt][nt] = __builtin_amdgcn_mfma_f32_16x16x32_bf16(a[mt], b[nt], acc[mt][nt], 0, 0, 0);
        __syncthreads();
    }

    #pragma unroll
    for (int mt = 0; mt < 2; mt++) {
        #pragma unroll
        for (int reg = 0; reg < 4; reg++) {
            int mg = blockM + wm + mt * 16 + quad * 4 + reg;
            if (mg >= NE) continue;
            #pragma unroll
            for (int nt = 0; nt < 4; nt++) {
                int nl = wn + nt * 16 + l16;
                float v = elu_f(acc[mt][nt][reg] + bias[nl]);
                out[(size_t)mg * Hdim + nl] = f2b(v);
            }
        }
    }
}

// ---------------- fused node update (both node types, one launch) ----------------
// Gather: agg = CSR-sum(msg rows)  -> LDS
// Phase 1: upd = elu([hb | agg] @ WTns^T + bns)  (stays in LDS)
// Phase 2: S = [hb | upd] @ Wcat^T ; Hh = hb @ Uh^T
// Gates (reset_after): z=sig(S_z+bz0+bz1), r=sig(S_r+br0+br1),
//   hh=tanh((S_h - Hh + b0h) + r*(Hh + b1h)), h = z*h + (1-z)*hh
__launch_bounds__(256)
__global__ void node_update_dual(unsigned short* __restrict__ hcb, unsigned short* __restrict__ hvb,
                                 float* __restrict__ hc, float* __restrict__ hv,
                                 const unsigned short* __restrict__ msg_vc,
                                 const unsigned short* __restrict__ msg_cv,
                                 const int* __restrict__ rp_c, const int* __restrict__ eid_c,
                                 const int* __restrict__ rp_v, const int* __restrict__ eid_v,
                                 const unsigned short* __restrict__ WTns_c, const float* __restrict__ bns_c,
                                 const unsigned short* __restrict__ WTns_v, const float* __restrict__ bns_v,
                                 const unsigned short* __restrict__ Wcat_c, const unsigned short* __restrict__ Uh_c,
                                 const unsigned short* __restrict__ Wcat_v, const unsigned short* __restrict__ Uh_v,
                                 const float* __restrict__ bg_c, const float* __restrict__ bg_v,
                                 int gridC) {
    __shared__ unsigned short sA[64 * 264];   // [row][k] K=256, stride 264
    __shared__ unsigned short sB[384 * 40];   // staged weight k-slices, stride 40
    const int tid = threadIdx.x;
    const int isV = (blockIdx.x >= gridC) ? 1 : 0;
    const int blockM = (isV ? (blockIdx.x - gridC) : blockIdx.x) * 64;
    unsigned short* hb = isV ? hvb : hcb;
    float* h = isV ? hv : hc;
    const unsigned short* msg = isV ? msg_cv : msg_vc;
    const int* rp = isV ? rp_v : rp_c;
    const int* eid = isV ? eid_v : eid_c;
    const unsigned short* WTns = isV ? WTns_v : WTns_c;
    const float* bns = isV ? bns_v : bns_c;
    const unsigned short* Wcat = isV ? Wcat_v : Wcat_c;
    const unsigned short* Uh = isV ? Uh_v : Uh_c;
    const float* bg = isV ? bg_v : bg_c;

    const int lane = tid & 63, wave = tid >> 6;
    const int quad = lane >> 4, l16 = lane & 15;
    const int wm16 = wave * 16;               // each wave owns a 16-row strip
    const int r = tid >> 2, ch = tid & 3;     // 4 threads per row
    const int node = blockM + r;

    // ---- stage hb rows into sA[:, 0:128) ----
    #pragma unroll
    for (int j = 0; j < 4; j++) {
        int k = ch * 8 + j * 32;
        *(s8v*)&sA[r * 264 + k] = *(const s8v*)&hb[(size_t)node * Hdim + k];
    }
    // ---- CSR gather-sum into sA[:, 128:256): thread sums cols [ch*32, ch*32+32) ----
    {
        float a32[32];
        #pragma unroll
        for (int i = 0; i < 32; i++) a32[i] = 0.0f;
        int b0 = rp[node], e0 = rp[node + 1];
        for (int j = b0; j < e0; j++) {
            const unsigned short* mr = msg + (size_t)eid[j] * Hdim + ch * 32;
            #pragma unroll
            for (int q = 0; q < 4; q++) {
                s8v v = *(const s8v*)&mr[q * 8];
                #pragma unroll
                for (int x = 0; x < 8; x++) a32[q * 8 + x] += b2f((unsigned short)v[x]);
            }
        }
        #pragma unroll
        for (int q = 0; q < 4; q++) {
            s8v w;
            #pragma unroll
            for (int x = 0; x < 8; x++) w[x] = (short)f2b(a32[q * 8 + x]);
            *(s8v*)&sA[r * 264 + 128 + ch * 32 + q * 8] = w;
        }
    }

    // ---- phase 1: ns GEMM, 8 col-tiles per wave strip ----
    f4v accN[8];
    #pragma unroll
    for (int nt = 0; nt < 8; nt++) accN[nt] = (f4v){0.f, 0.f, 0.f, 0.f};
    for (int kt = 0; kt < 8; kt++) {
        #pragma unroll
        for (int p = 0; p < 2; p++) {
            int n = (tid >> 2) + p * 64;
            *(s8v*)&sB[n * 40 + ch * 8] = *(const s8v*)&WTns[(size_t)n * 256 + kt * 32 + ch * 8];
        }
        __syncthreads();
        s8v a = *(const s8v*)&sA[(wm16 + l16) * 264 + kt * 32 + quad * 8];
        #pragma unroll
        for (int nt = 0; nt < 8; nt++) {
            s8v b = *(const s8v*)&sB[(nt * 16 + l16) * 40 + quad * 8];
            accN[nt] = __builtin_amdgcn_mfma_f32_16x16x32_bf16(a, b, accN[nt], 0, 0, 0);
        }
        __syncthreads();
    }
    // write upd into own wave's rows, sA cols [128:256)
    #pragma unroll
    for (int nt = 0; nt < 8; nt++) {
        #pragma unroll
        for (int reg = 0; reg < 4; reg++) {
            int row = wm16 + quad * 4 + reg;
            int col = nt * 16 + l16;
            float v = elu_f(accN[nt][reg] + bns[col]);
            sA[row * 264 + 128 + col] = f2b(v);
        }
    }

    // ---- phase 2a: S = [hb | upd] @ Wcat^T (24 col-tiles) ----
    f4v accS[24];
    #pragma unroll
    for (int nt = 0; nt < 24; nt++) accS[nt] = (f4v){0.f, 0.f, 0.f, 0.f};
    for (int kt = 0; kt < 8; kt++) {
        #pragma unroll
        for (int p = 0; p < 6; p++) {
            int n = (tid >> 2) + p * 64;
            *(s8v*)&sB[n * 40 + ch * 8] = *(const s8v*)&Wcat[(size_t)n * 256 + kt * 32 + ch * 8];
        }
        __syncthreads();
        s8v a = *(const s8v*)&sA[(wm16 + l16) * 264 + kt * 32 + quad * 8];
        #pragma unroll
        for (int nt = 0; nt < 24; nt++) {
            s8v b = *(const s8v*)&sB[(nt * 16 + l16) * 40 + quad * 8];
            accS[nt] = __builtin_amdgcn_mfma_f32_16x16x32_bf16(a, b, accS[nt], 0, 0, 0);
        }
        __syncthreads();
    }

    // ---- phase 2b: Hh = hb @ Uh^T (8 col-tiles, K=128) ----
    f4v accH[8];
    #pragma unroll
    for (int nt = 0; nt < 8; nt++) accH[nt] = (f4v){0.f, 0.f, 0.f, 0.f};
    for (int kt = 0; kt < 4; kt++) {
        #pragma unroll
        for (int p = 0; p < 2; p++) {
            int n = (tid >> 2) + p * 64;
            *(s8v*)&sB[n * 40 + ch * 8] = *(const s8v*)&Uh[(size_t)n * 128 + kt * 32 + ch * 8];
        }
        __syncthreads();
        s8v a = *(const s8v*)&sA[(wm16 + l16) * 264 + kt * 32 + quad * 8];
        #pragma unroll
        for (int nt = 0; nt < 8; nt++) {
            s8v b = *(const s8v*)&sB[(nt * 16 + l16) * 40 + quad * 8];
            accH[nt] = __builtin_amdgcn_mfma_f32_16x16x32_bf16(a, b, accH[nt], 0, 0, 0);
        }
        __syncthreads();
    }

    // ---- gates ----
    #pragma unroll
    for (int j = 0; j < 8; j++) {
        int t = j * 16 + l16;
        float bz = bg[t]       + bg[384 + t];
        float br = bg[128 + t] + bg[512 + t];
        float b0h = bg[256 + t];
        float b1h = bg[640 + t];
        #pragma unroll
        for (int reg = 0; reg < 4; reg++) {
            int row = blockM + wm16 + quad * 4 + reg;
            float Sz = accS[j][reg]      + bz;
            float Sr = accS[8 + j][reg]  + br;
            float Sh = accS[16 + j][reg];
            float Hh = accH[j][reg];
            float z = sigm_f(Sz);
            float rr = sigm_f(Sr);
            float hh = tanhf((Sh - Hh + b0h) + rr * (Hh + b1h));
            float hold = h[(size_t)row * Hdim + t];
            float hn = z * hold + (1.0f - z) * hh;
            h[(size_t)row * Hdim + t] = hn;
            hb[(size_t)row * Hdim + t] = f2b(hn);
        }
    }
}

// ---------------- final: out[i] = dot(hv[i], Wf) + bf ----------------
__global__ void final_kernel(const float* __restrict__ hv, const float* __restrict__ Wf,
                             const float* __restrict__ bf, float* __restrict__ out) {
    int node = blockIdx.x * 4 + (threadIdx.x >> 6);
    int lane = threadIdx.x & 63;
    const float* row = hv + (size_t)node * Hdim;
    float s = row[lane] * Wf[lane] + row[lane + 64] * Wf[lane + 64];
    #pragma unroll
    for (int off = 32; off > 0; off >>= 1) s += __shfl_xor(s, off);
    if (lane == 0) out[node] = s + bf[0];
}

extern "C" void kernel_launch(void* const* d_in, const int* in_sizes, int n_in,
                              void* d_out, int out_size, void* d_ws, size_t ws_size,
                              hipStream_t stream) {
    const float* cf      = (const float*)d_in[0];
    const float* vf      = (const float*)d_in[1];
    const int*   c2v_src = (const int*)d_in[2];
    const int*   c2v_tgt = (const int*)d_in[3];
    const int*   v2c_src = (const int*)d_in[4];
    const int*   v2c_tgt = (const int*)d_in[5];
    const float* Wc_in   = (const float*)d_in[6];
    const float* bc_in   = (const float*)d_in[7];
    const float* Wv_in   = (const float*)d_in[8];
    const float* bv_in   = (const float*)d_in[9];
    const float* gc_ln   = (const float*)d_in[10];
    const float* bc_ln   = (const float*)d_in[11];
    const float* gv_ln   = (const float*)d_in[12];
    const float* bv_ln   = (const float*)d_in[13];
    const float* Wmsg_c  = (const float*)d_in[14];
    const float* bmsg_c  = (const float*)d_in[15];
    const float* Wmsg_v  = (const float*)d_in[16];
    const float* bmsg_v  = (const float*)d_in[17];
    const float* Wns_c   = (const float*)d_in[18];
    const float* bns_c   = (const float*)d_in[19];
    const float* Wns_v   = (const float*)d_in[20];
    const float* bns_v   = (const float*)d_in[21];
    const float* Wg_c    = (const float*)d_in[22];
    const float* Ug_c    = (const float*)d_in[23];
    const float* bg_c    = (const float*)d_in[24];
    const float* Wg_v    = (const float*)d_in[25];
    const float* Ug_v    = (const float*)d_in[26];
    const float* bg_v    = (const float*)d_in[27];
    const float* Wf      = (const float*)d_in[28];
    const float* bf      = (const float*)d_in[29];
    float* out = (float*)d_out;

    // ---- workspace carve (256B-aligned) ----
    char* p = (char*)d_ws;
    #define CARVE(name, type, count) type* name = (type*)p; p += (((size_t)(count) * sizeof(type)) + 255) & ~(size_t)255;
    CARVE(hc,     float, NCn * Hdim)
    CARVE(hv,     float, NVn * Hdim)
    CARVE(msg_vc, unsigned short, NE * Hdim)
    CARVE(msg_cv, unsigned short, NE * Hdim)
    CARVE(hc_b,   unsigned short, NCn * Hdim)
    CARVE(hv_b,   unsigned short, NVn * Hdim)
    CARVE(WTmsg_c, unsigned short, 128 * 256)
    CARVE(WTmsg_v, unsigned short, 128 * 256)
    CARVE(WTns_c,  unsigned short, 128 * 256)
    CARVE(WTns_v,  unsigned short, 128 * 256)
    CARVE(Wcat_c,  unsigned short, 384 * 256)
    CARVE(Uh_c,    unsigned short, 128 * 128)
    CARVE(Wcat_v,  unsigned short, 384 * 256)
    CARVE(Uh_v,    unsigned short, 128 * 128)
    CARVE(rp_c,  int, NCn + 8)
    CARVE(rp_v,  int, NVn + 8)
    CARVE(eid_c, int, NE)
    CARVE(eid_v, int, NE)
    CARVE(cnts,  int, 48000)
    #undef CARVE
    int* cnt_c  = cnts;
    int* cnt_v  = cnts + NCn;
    int* fill_c = cnts + NCn + NVn;
    int* fill_v = cnts + 2 * NCn + NVn;

    // ---- once-per-call prep (7 dispatches) ----
    prep_weights<<<(4 * 32768 + 2 * (384 * 256 + 128 * 128) + 255) / 256, 256, 0, stream>>>(
        Wmsg_c, Wmsg_v, Wns_c, Wns_v, Wg_c, Ug_c, Wg_v, Ug_v,
        WTmsg_c, WTmsg_v, WTns_c, WTns_v, Wcat_c, Uh_c, Wcat_v, Uh_v);
    zero_int_kernel<<<(48000 + 255) / 256, 256, 0, stream>>>(cnts, 48000);
    hist_kernel<<<(NE + 255) / 256, 256, 0, stream>>>(v2c_tgt, c2v_tgt, cnt_c, cnt_v);
    scan_kernel<<<1, 1024, 0, stream>>>(cnt_c, rp_c, NCn);
    scan_kernel<<<1, 1024, 0, stream>>>(cnt_v, rp_v, NVn);
    fill_kernel<<<(NE + 255) / 256, 256, 0, stream>>>(v2c_tgt, c2v_tgt, rp_c, rp_v,
                                                      fill_c, fill_v, eid_c, eid_v);
    init_kernel<<<NCn + NVn, 64, 0, stream>>>(cf, vf, Wc_in, bc_in, Wv_in, bv_in,
                                              gc_ln, bc_ln, gv_ln, bv_ln, hc, hv, hc_b, hv_b);

    const int gridE = (NE + 63) / 64;   // 938
    const int gridC = NCn / 64;         // 125
    const int gridV = NVn / 64;         // 250

    for (int it = 0; it < LITERS; it++) {
        edge_gemm_dual<<<2 * gridE, 256, 0, stream>>>(
            hv_b, hc_b, v2c_src, v2c_tgt, c2v_src, c2v_tgt,
            WTmsg_c, WTmsg_v, bmsg_c, bmsg_v, msg_vc, msg_cv, gridE);
        node_update_dual<<<gridC + gridV, 256, 0, stream>>>(
            hc_b, hv_b, hc, hv, msg_vc, msg_cv,
            rp_c, eid_c, rp_v, eid_v,
            WTns_c, bns_c, WTns_v, bns_v,
            Wcat_c, Uh_c, Wcat_v, Uh_v, bg_c, bg_v, gridC);
    }

    final_kernel<<<NVn / 4, 256, 0, stream>>>(hv, Wf, bf, out);
}